// Round 2
// baseline (578.384 us; speedup 1.0000x reference)
//
#include <hip/hip_runtime.h>
#include <math.h>

typedef unsigned short u16;
typedef __attribute__((ext_vector_type(8))) short bf16x8;
typedef __attribute__((ext_vector_type(4))) float f32x4;

#define MFMA16(a, b, c) __builtin_amdgcn_mfma_f32_16x16x32_bf16(a, b, c, 0, 0, 0)

__device__ __forceinline__ void gld16(const void* g, void* l) {
  __builtin_amdgcn_global_load_lds((const __attribute__((address_space(1))) void*)g,
                                   (__attribute__((address_space(3))) void*)l, 16, 0, 0);
}

__device__ __forceinline__ u16 f2bf(float f) {  // RNE f32->bf16 (finite inputs)
  unsigned u = __float_as_uint(f);
  u += 0x7fffu + ((u >> 16) & 1u);
  return (u16)(u >> 16);
}

// ---------- 1) cast 4 weight matrices [1024x1024] f32 -> bf16 ----------
__global__ __launch_bounds__(256) void k_castw(const float* __restrict__ wq, const float* __restrict__ wk,
                                               const float* __restrict__ wv, const float* __restrict__ wo,
                                               u16* __restrict__ dst) {
  int t = blockIdx.x * 256 + threadIdx.x;   // 0 .. 2^20-1  (float4 units)
  int which = t >> 18;                      // 2^18 float4 per weight
  int off = (t & 0x3ffff) << 2;
  const float* src = (which == 0) ? wq : (which == 1) ? wk : (which == 2) ? wv : wo;
  float4 v = *reinterpret_cast<const float4*>(src + off);
  ushort4 o;
  o.x = f2bf(v.x); o.y = f2bf(v.y); o.z = f2bf(v.z); o.w = f2bf(v.w);
  *reinterpret_cast<ushort4*>(dst + ((size_t)which << 20) + off) = o;
}

// ---------- 2) LayerNorm -> bf16, one block per row of 1024 ----------
__global__ __launch_bounds__(256) void k_ln(const float* __restrict__ x, const float* __restrict__ gamma,
                                            const float* __restrict__ beta, u16* __restrict__ xn) {
  const int row = blockIdx.x, tid = threadIdx.x;
  const int lane = tid & 63, w = tid >> 6;
  const float* xr = x + (size_t)row * 1024;
  float4 v = *reinterpret_cast<const float4*>(xr + tid * 4);
  float s = v.x + v.y + v.z + v.w;
  float s2 = v.x * v.x + v.y * v.y + v.z * v.z + v.w * v.w;
  #pragma unroll
  for (int m = 1; m < 64; m <<= 1) { s += __shfl_xor(s, m); s2 += __shfl_xor(s2, m); }
  __shared__ float ps[4], pq[4];
  if (lane == 0) { ps[w] = s; pq[w] = s2; }
  __syncthreads();
  float S = ps[0] + ps[1] + ps[2] + ps[3];
  float S2 = pq[0] + pq[1] + pq[2] + pq[3];
  float mu = S * (1.f / 1024.f);
  float var = S2 * (1.f / 1024.f) - mu * mu;
  float rstd = rsqrtf(var + 1e-5f);
  float4 g = *reinterpret_cast<const float4*>(gamma + tid * 4);
  float4 bt = *reinterpret_cast<const float4*>(beta + tid * 4);
  ushort4 o;
  o.x = f2bf((v.x - mu) * rstd * g.x + bt.x);
  o.y = f2bf((v.y - mu) * rstd * g.y + bt.y);
  o.z = f2bf((v.z - mu) * rstd * g.z + bt.z);
  o.w = f2bf((v.w - mu) * rstd * g.w + bt.w);
  *reinterpret_cast<ushort4*>(xn + (size_t)row * 1024 + tid * 4) = o;
}

// ---------- 3) QKV projection: C[m][n] = sum_k xn[m][k] * W[n][k]  (gemm_bt 128x128) ----------
__global__ __launch_bounds__(256) void k_gemm_qkv(const u16* __restrict__ xn,
    const u16* __restrict__ wqb, const u16* __restrict__ wkb, const u16* __restrict__ wvb,
    const float* __restrict__ bq, const float* __restrict__ bk, const float* __restrict__ bv,
    u16* __restrict__ qo, u16* __restrict__ ko, u16* __restrict__ vo) {
  __shared__ __align__(16) u16 lA[128 * 32];
  __shared__ __align__(16) u16 lB[128 * 32];
  const int tid = threadIdx.x;
  const int w = tid >> 6, lane = tid & 63;
  const int wr = w >> 1, wc = w & 1;
  const int lane15 = lane & 15, lgrp = lane >> 4;
  const int m0 = blockIdx.y * 128, n0 = blockIdx.x * 128;
  const int z = blockIdx.z;
  const u16* Bt = (z == 0) ? wqb : (z == 1) ? wkb : wvb;

  f32x4 zero = {0.f, 0.f, 0.f, 0.f};
  f32x4 acc[4][4];
  #pragma unroll
  for (int i = 0; i < 4; i++)
    #pragma unroll
    for (int j = 0; j < 4; j++) acc[i][j] = zero;

  const int srow = w * 16 + (lane >> 2);
  const int scol = (lane & 3) * 8;
  for (int kt = 0; kt < 32; kt++) {
    const int k0 = kt * 32;
    #pragma unroll
    for (int c = 0; c < 2; c++) {
      gld16(xn + (size_t)(m0 + c * 64 + srow) * 1024 + k0 + scol, (char*)lA + c * 4096 + w * 1024);
      gld16(Bt + (size_t)(n0 + c * 64 + srow) * 1024 + k0 + scol, (char*)lB + c * 4096 + w * 1024);
    }
    __syncthreads();
    bf16x8 aF[4], bF[4];
    #pragma unroll
    for (int f = 0; f < 4; f++) {
      aF[f] = *reinterpret_cast<const bf16x8*>(&lA[(wr * 64 + f * 16 + lane15) * 32 + lgrp * 8]);
      bF[f] = *reinterpret_cast<const bf16x8*>(&lB[(wc * 64 + f * 16 + lane15) * 32 + lgrp * 8]);
    }
    #pragma unroll
    for (int fm = 0; fm < 4; fm++)
      #pragma unroll
      for (int fn = 0; fn < 4; fn++)
        acc[fm][fn] = MFMA16(aF[fm], bF[fn], acc[fm][fn]);
    __syncthreads();
  }

  const float* bvec = (z == 0) ? bq : (z == 1) ? bk : bv;
  u16* dst = (z == 0) ? qo : (z == 1) ? ko : vo;
  #pragma unroll
  for (int fm = 0; fm < 4; fm++)
    #pragma unroll
    for (int fn = 0; fn < 4; fn++) {
      const int n = n0 + wc * 64 + fn * 16 + lane15;
      const int h = n >> 6, d = n & 63;
      const float bn = bvec[n];
      #pragma unroll
      for (int j = 0; j < 4; j++) {
        const int m = m0 + wr * 64 + fm * 16 + lgrp * 4 + j;
        const int b = m >> 10, lq = m & 1023;
        dst[(((size_t)(b * 16 + h)) * 1024 + lq) * 64 + d] = f2bf(acc[fm][fn][j] + bn);
      }
    }
}

// ---------- 4) V [B,H,L,D] -> Vt [B,H,D,L] ----------
__global__ __launch_bounds__(256) void k_transpose_v(const u16* __restrict__ V, u16* __restrict__ Vt) {
  __shared__ u16 t[64][64];
  const int bh = blockIdx.y, l0 = blockIdx.x * 64;
  const int tid = threadIdx.x;
  const int r = tid >> 2, c0 = (tid & 3) * 16;
  const u16* src = V + ((size_t)bh * 1024 + l0 + r) * 64 + c0;
  __align__(16) u16 tmp[16];
  *reinterpret_cast<uint4*>(tmp) = *reinterpret_cast<const uint4*>(src);
  *reinterpret_cast<uint4*>(tmp + 8) = *reinterpret_cast<const uint4*>(src + 8);
  #pragma unroll
  for (int i = 0; i < 16; i++) t[c0 + i][r] = tmp[i];
  __syncthreads();
  __align__(16) u16 o[16];
  #pragma unroll
  for (int i = 0; i < 16; i++) o[i] = t[r][c0 + i];
  u16* dst = Vt + ((size_t)bh * 64 + r) * 1024 + l0 + c0;
  *reinterpret_cast<uint4*>(dst) = *reinterpret_cast<const uint4*>(o);
  *reinterpret_cast<uint4*>(dst + 8) = *reinterpret_cast<const uint4*>(o + 8);
}

// ---------- 5) fused flash attention ----------
// grid (L/64, B*H); block 256 = 4 waves; wave w handles 16 q-rows, KBLK=32.
__global__ __launch_bounds__(256) void k_attn(const u16* __restrict__ Q, const u16* __restrict__ K,
    const u16* __restrict__ Vt, const float* __restrict__ bias, const int* __restrict__ mask,
    const float* __restrict__ gate, u16* __restrict__ O) {
  __shared__ __align__(16) u16 lK[32 * 64];       // [key][d]
  __shared__ __align__(16) u16 lV[64 * 32];       // [d][key]
  __shared__ __align__(16) u16 lP[4 * 16 * 32];   // per-wave [16 q][32 k]
  const int tid = threadIdx.x;
  const int w = tid >> 6, lane = tid & 63;
  const int lane15 = lane & 15, lgrp = lane >> 4;
  const int bh = blockIdx.y;
  const int b = bh >> 4, h = bh & 15;
  const int q0 = blockIdx.x * 64 + w * 16;
  const float gateh = gate[h];
  const int* mb = mask + b * 1024;
  const float* biasq = bias + ((size_t)bh << 20);

  bf16x8 qf[2];
  #pragma unroll
  for (int kk = 0; kk < 2; kk++)
    qf[kk] = *reinterpret_cast<const bf16x8*>(Q + ((size_t)bh * 1024 + q0 + lane15) * 64 + kk * 32 + lgrp * 8);

  f32x4 zero = {0.f, 0.f, 0.f, 0.f};
  float m_i[4], l_i[4];
  f32x4 accO[4];
  #pragma unroll
  for (int j = 0; j < 4; j++) { m_i[j] = -INFINITY; l_i[j] = 0.f; }
  #pragma unroll
  for (int f = 0; f < 4; f++) accO[f] = zero;

  const int krow = tid >> 3, kcol = (tid & 7) * 8;   // K tile [32][64]: 1 gld16/thread
  const int vrow = tid >> 2, vcol = (tid & 3) * 8;   // Vt tile [64][32]: 1 gld16/thread
  const size_t kbase = (size_t)bh * 1024 * 64;
  const size_t vbase = (size_t)bh * 64 * 1024;

  for (int kb = 0; kb < 1024; kb += 32) {
    gld16(K + kbase + (size_t)(kb + krow) * 64 + kcol, (char*)lK + w * 1024);
    gld16(Vt + vbase + (size_t)vrow * 1024 + kb + vcol, (char*)lV + w * 1024);
    __syncthreads();

    // S = Q K^T  (16 q x 32 k)
    f32x4 s[2];
    #pragma unroll
    for (int fn = 0; fn < 2; fn++) {
      bf16x8 kf0 = *reinterpret_cast<const bf16x8*>(&lK[(fn * 16 + lane15) * 64 + lgrp * 8]);
      bf16x8 kf1 = *reinterpret_cast<const bf16x8*>(&lK[(fn * 16 + lane15) * 64 + 32 + lgrp * 8]);
      s[fn] = MFMA16(qf[0], kf0, zero);
      s[fn] = MFMA16(qf[1], kf1, s[fn]);
    }
    // scale + gate*bias + key mask
    int mk[2];
    float pmax[4] = {-INFINITY, -INFINITY, -INFINITY, -INFINITY};
    #pragma unroll
    for (int fn = 0; fn < 2; fn++) {
      const int kg = kb + fn * 16 + lane15;
      mk[fn] = mb[kg];
      #pragma unroll
      for (int j = 0; j < 4; j++) {
        const int qg = q0 + lgrp * 4 + j;
        float lg = s[fn][j] * 0.125f + gateh * biasq[(size_t)qg * 1024 + kg];
        lg = mk[fn] ? lg : -INFINITY;
        s[fn][j] = lg;
        pmax[j] = fmaxf(pmax[j], lg);
      }
    }
    #pragma unroll
    for (int j = 0; j < 4; j++)
      #pragma unroll
      for (int xm = 1; xm < 16; xm <<= 1)
        pmax[j] = fmaxf(pmax[j], __shfl_xor(pmax[j], xm));

    float corr[4], mnew[4], rs[4];
    #pragma unroll
    for (int j = 0; j < 4; j++) {
      mnew[j] = fmaxf(m_i[j], pmax[j]);
      corr[j] = (m_i[j] == -INFINITY) ? 0.f : __expf(m_i[j] - mnew[j]);
      rs[j] = 0.f;
    }
    #pragma unroll
    for (int fn = 0; fn < 2; fn++)
      #pragma unroll
      for (int j = 0; j < 4; j++) {
        float p = mk[fn] ? __expf(s[fn][j] - mnew[j]) : 0.f;
        rs[j] += p;
        lP[w * 512 + (lgrp * 4 + j) * 32 + fn * 16 + lane15] = f2bf(p);
      }
    #pragma unroll
    for (int j = 0; j < 4; j++) {
      #pragma unroll
      for (int xm = 1; xm < 16; xm <<= 1) rs[j] += __shfl_xor(rs[j], xm);
      l_i[j] = l_i[j] * corr[j] + rs[j];
      m_i[j] = mnew[j];
    }
    #pragma unroll
    for (int f = 0; f < 4; f++)
      #pragma unroll
      for (int j = 0; j < 4; j++) accO[f][j] *= corr[j];

    // PV: accO[16 q][64 d] += P[16][32] @ V[32][64]
    bf16x8 pf = *reinterpret_cast<const bf16x8*>(&lP[w * 512 + lane15 * 32 + lgrp * 8]);
    #pragma unroll
    for (int f = 0; f < 4; f++) {
      bf16x8 vf = *reinterpret_cast<const bf16x8*>(&lV[(f * 16 + lane15) * 32 + lgrp * 8]);
      accO[f] = MFMA16(pf, vf, accO[f]);
    }
    __syncthreads();
  }

  // epilogue: /l, * query-mask; O as [B,L,H,D] bf16
  #pragma unroll
  for (int j = 0; j < 4; j++) {
    const int lq = q0 + lgrp * 4 + j;
    const float inv = (l_i[j] > 0.f) ? 1.f / l_i[j] : 0.f;
    const float mfq = mb[lq] ? 1.f : 0.f;
    #pragma unroll
    for (int f = 0; f < 4; f++) {
      const int d = f * 16 + lane15;
      O[(((size_t)(b * 1024 + lq)) * 16 + h) * 64 + d] = f2bf(accO[f][j] * inv * mfq);
    }
  }
}

// ---------- 6) out = x + O @ Wo^T + bo ----------
__global__ __launch_bounds__(256) void k_gemm_out(const u16* __restrict__ A, const u16* __restrict__ Bt,
    const float* __restrict__ bo, const float* __restrict__ x, float* __restrict__ out) {
  __shared__ __align__(16) u16 lA[128 * 32];
  __shared__ __align__(16) u16 lB[128 * 32];
  const int tid = threadIdx.x;
  const int w = tid >> 6, lane = tid & 63;
  const int wr = w >> 1, wc = w & 1;
  const int lane15 = lane & 15, lgrp = lane >> 4;
  const int m0 = blockIdx.y * 128, n0 = blockIdx.x * 128;

  f32x4 zero = {0.f, 0.f, 0.f, 0.f};
  f32x4 acc[4][4];
  #pragma unroll
  for (int i = 0; i < 4; i++)
    #pragma unroll
    for (int j = 0; j < 4; j++) acc[i][j] = zero;

  const int srow = w * 16 + (lane >> 2);
  const int scol = (lane & 3) * 8;
  for (int kt = 0; kt < 32; kt++) {
    const int k0 = kt * 32;
    #pragma unroll
    for (int c = 0; c < 2; c++) {
      gld16(A + (size_t)(m0 + c * 64 + srow) * 1024 + k0 + scol, (char*)lA + c * 4096 + w * 1024);
      gld16(Bt + (size_t)(n0 + c * 64 + srow) * 1024 + k0 + scol, (char*)lB + c * 4096 + w * 1024);
    }
    __syncthreads();
    bf16x8 aF[4], bF[4];
    #pragma unroll
    for (int f = 0; f < 4; f++) {
      aF[f] = *reinterpret_cast<const bf16x8*>(&lA[(wr * 64 + f * 16 + lane15) * 32 + lgrp * 8]);
      bF[f] = *reinterpret_cast<const bf16x8*>(&lB[(wc * 64 + f * 16 + lane15) * 32 + lgrp * 8]);
    }
    #pragma unroll
    for (int fm = 0; fm < 4; fm++)
      #pragma unroll
      for (int fn = 0; fn < 4; fn++)
        acc[fm][fn] = MFMA16(aF[fm], bF[fn], acc[fm][fn]);
    __syncthreads();
  }

  #pragma unroll
  for (int fm = 0; fm < 4; fm++)
    #pragma unroll
    for (int fn = 0; fn < 4; fn++) {
      const int n = n0 + wc * 64 + fn * 16 + lane15;
      const float bn = bo[n];
      #pragma unroll
      for (int j = 0; j < 4; j++) {
        const int m = m0 + wr * 64 + fm * 16 + lgrp * 4 + j;
        out[(size_t)m * 1024 + n] = acc[fm][fn][j] + bn + x[(size_t)m * 1024 + n];
      }
    }
}

extern "C" void kernel_launch(void* const* d_in, const int* in_sizes, int n_in,
                              void* d_out, int out_size, void* d_ws, size_t ws_size,
                              hipStream_t stream) {
  const float* x     = (const float*)d_in[0];
  const float* bias  = (const float*)d_in[1];
  const int*   mask  = (const int*)d_in[2];
  const float* Wq    = (const float*)d_in[3];
  const float* bq    = (const float*)d_in[4];
  const float* Wk    = (const float*)d_in[5];
  const float* bk    = (const float*)d_in[6];
  const float* Wv    = (const float*)d_in[7];
  const float* bv    = (const float*)d_in[8];
  const float* Wo    = (const float*)d_in[9];
  const float* bo    = (const float*)d_in[10];
  const float* gamma = (const float*)d_in[11];
  const float* beta  = (const float*)d_in[12];
  const float* gate  = (const float*)d_in[13];
  float* out = (float*)d_out;

  u16* wsu  = (u16*)d_ws;
  u16* wqb  = wsu;                  // 1M u16 each
  u16* wkb  = wqb  + (1u << 20);
  u16* wvb  = wkb  + (1u << 20);
  u16* wob  = wvb  + (1u << 20);
  u16* xnb  = wob  + (1u << 20);    // [4096][1024]
  u16* qb   = xnb  + (4u << 20);    // [B,H,L,D]
  u16* kbuf = qb   + (4u << 20);    // [B,H,L,D]
  u16* vb   = kbuf + (4u << 20);    // [B,H,L,D]
  u16* vtb  = vb   + (4u << 20);    // [B,H,D,L]
  u16* ob   = vtb  + (4u << 20);    // [B,L,H*D]
  // total 28M u16 = 56 MB of d_ws

  k_castw<<<4096, 256, 0, stream>>>(Wq, Wk, Wv, Wo, wqb);
  k_ln<<<4096, 256, 0, stream>>>(x, gamma, beta, xnb);
  k_gemm_qkv<<<dim3(8, 32, 3), 256, 0, stream>>>(xnb, wqb, wkb, wvb, bq, bk, bv, qb, kbuf, vb);
  k_transpose_v<<<dim3(16, 64), 256, 0, stream>>>(vb, vtb);
  k_attn<<<dim3(16, 64), 256, 0, stream>>>(qb, kbuf, vtb, bias, mask, gate, ob);
  k_gemm_out<<<dim3(8, 32), 256, 0, stream>>>(ob, wob, bo, x, out);
}

// Round 4
// 541.998 us; speedup vs baseline: 1.0671x; 1.0671x over previous
//
#include <hip/hip_runtime.h>
#include <math.h>

typedef unsigned short u16;
typedef __attribute__((ext_vector_type(8))) short bf16x8;
typedef __attribute__((ext_vector_type(4))) float f32x4;

#define MFMA16(a, b, c) __builtin_amdgcn_mfma_f32_16x16x32_bf16(a, b, c, 0, 0, 0)

__device__ __forceinline__ void gld16(const void* g, void* l) {
  __builtin_amdgcn_global_load_lds((const __attribute__((address_space(1))) void*)g,
                                   (__attribute__((address_space(3))) void*)l, 16, 0, 0);
}

__device__ __forceinline__ u16 f2bf(float f) {  // RNE f32->bf16 (finite inputs)
  unsigned u = __float_as_uint(f);
  u += 0x7fffu + ((u >> 16) & 1u);
  return (u16)(u >> 16);
}

// ---------- 1) cast 4 weight matrices [1024x1024] f32 -> bf16 ----------
__global__ __launch_bounds__(256) void k_castw(const float* __restrict__ wq, const float* __restrict__ wk,
                                               const float* __restrict__ wv, const float* __restrict__ wo,
                                               u16* __restrict__ dst) {
  int t = blockIdx.x * 256 + threadIdx.x;   // 0 .. 2^20-1  (float4 units)
  int which = t >> 18;                      // 2^18 float4 per weight
  int off = (t & 0x3ffff) << 2;
  const float* src = (which == 0) ? wq : (which == 1) ? wk : (which == 2) ? wv : wo;
  float4 v = *reinterpret_cast<const float4*>(src + off);
  ushort4 o;
  o.x = f2bf(v.x); o.y = f2bf(v.y); o.z = f2bf(v.z); o.w = f2bf(v.w);
  *reinterpret_cast<ushort4*>(dst + ((size_t)which << 20) + off) = o;
}

// ---------- 2) LayerNorm -> bf16, one block per row of 1024 ----------
__global__ __launch_bounds__(256) void k_ln(const float* __restrict__ x, const float* __restrict__ gamma,
                                            const float* __restrict__ beta, u16* __restrict__ xn) {
  const int row = blockIdx.x, tid = threadIdx.x;
  const int lane = tid & 63, w = tid >> 6;
  const float* xr = x + (size_t)row * 1024;
  float4 v = *reinterpret_cast<const float4*>(xr + tid * 4);
  float s = v.x + v.y + v.z + v.w;
  float s2 = v.x * v.x + v.y * v.y + v.z * v.z + v.w * v.w;
  #pragma unroll
  for (int m = 1; m < 64; m <<= 1) { s += __shfl_xor(s, m); s2 += __shfl_xor(s2, m); }
  __shared__ float ps[4], pq[4];
  if (lane == 0) { ps[w] = s; pq[w] = s2; }
  __syncthreads();
  float S = ps[0] + ps[1] + ps[2] + ps[3];
  float S2 = pq[0] + pq[1] + pq[2] + pq[3];
  float mu = S * (1.f / 1024.f);
  float var = S2 * (1.f / 1024.f) - mu * mu;
  float rstd = rsqrtf(var + 1e-5f);
  float4 g = *reinterpret_cast<const float4*>(gamma + tid * 4);
  float4 bt = *reinterpret_cast<const float4*>(beta + tid * 4);
  ushort4 o;
  o.x = f2bf((v.x - mu) * rstd * g.x + bt.x);
  o.y = f2bf((v.y - mu) * rstd * g.y + bt.y);
  o.z = f2bf((v.z - mu) * rstd * g.z + bt.z);
  o.w = f2bf((v.w - mu) * rstd * g.w + bt.w);
  *reinterpret_cast<ushort4*>(xn + (size_t)row * 1024 + tid * 4) = o;
}

// ---------- 3) QKV projection: C[m][n] = sum_k xn[m][k] * W[n][k]  (gemm_bt 128x128) ----------
__global__ __launch_bounds__(256) void k_gemm_qkv(const u16* __restrict__ xn,
    const u16* __restrict__ wqb, const u16* __restrict__ wkb, const u16* __restrict__ wvb,
    const float* __restrict__ bq, const float* __restrict__ bk, const float* __restrict__ bv,
    u16* __restrict__ qo, u16* __restrict__ ko, u16* __restrict__ vo) {
  __shared__ __align__(16) u16 lA[128 * 32];
  __shared__ __align__(16) u16 lB[128 * 32];
  const int tid = threadIdx.x;
  const int w = tid >> 6, lane = tid & 63;
  const int wr = w >> 1, wc = w & 1;
  const int lane15 = lane & 15, lgrp = lane >> 4;
  const int m0 = blockIdx.y * 128, n0 = blockIdx.x * 128;
  const int z = blockIdx.z;
  const u16* Bt = (z == 0) ? wqb : (z == 1) ? wkb : wvb;

  f32x4 zero = {0.f, 0.f, 0.f, 0.f};
  f32x4 acc[4][4];
  #pragma unroll
  for (int i = 0; i < 4; i++)
    #pragma unroll
    for (int j = 0; j < 4; j++) acc[i][j] = zero;

  const int srow = w * 16 + (lane >> 2);
  const int scol = (lane & 3) * 8;
  for (int kt = 0; kt < 32; kt++) {
    const int k0 = kt * 32;
    #pragma unroll
    for (int c = 0; c < 2; c++) {
      gld16(xn + (size_t)(m0 + c * 64 + srow) * 1024 + k0 + scol, (char*)lA + c * 4096 + w * 1024);
      gld16(Bt + (size_t)(n0 + c * 64 + srow) * 1024 + k0 + scol, (char*)lB + c * 4096 + w * 1024);
    }
    __syncthreads();
    bf16x8 aF[4], bF[4];
    #pragma unroll
    for (int f = 0; f < 4; f++) {
      aF[f] = *reinterpret_cast<const bf16x8*>(&lA[(wr * 64 + f * 16 + lane15) * 32 + lgrp * 8]);
      bF[f] = *reinterpret_cast<const bf16x8*>(&lB[(wc * 64 + f * 16 + lane15) * 32 + lgrp * 8]);
    }
    #pragma unroll
    for (int fm = 0; fm < 4; fm++)
      #pragma unroll
      for (int fn = 0; fn < 4; fn++)
        acc[fm][fn] = MFMA16(aF[fm], bF[fn], acc[fm][fn]);
    __syncthreads();
  }

  const float* bvec = (z == 0) ? bq : (z == 1) ? bk : bv;
  u16* dst = (z == 0) ? qo : (z == 1) ? ko : vo;
  #pragma unroll
  for (int fm = 0; fm < 4; fm++)
    #pragma unroll
    for (int fn = 0; fn < 4; fn++) {
      const int n = n0 + wc * 64 + fn * 16 + lane15;
      const int h = n >> 6, d = n & 63;
      const float bn = bvec[n];
      #pragma unroll
      for (int j = 0; j < 4; j++) {
        const int m = m0 + wr * 64 + fm * 16 + lgrp * 4 + j;
        const int b = m >> 10, lq = m & 1023;
        dst[(((size_t)(b * 16 + h)) * 1024 + lq) * 64 + d] = f2bf(acc[fm][fn][j] + bn);
      }
    }
}

// ---------- 4) V [B,H,L,D] -> Vt [B,H,D,L] ----------
__global__ __launch_bounds__(256) void k_transpose_v(const u16* __restrict__ V, u16* __restrict__ Vt) {
  __shared__ u16 t[64][64];
  const int bh = blockIdx.y, l0 = blockIdx.x * 64;
  const int tid = threadIdx.x;
  const int r = tid >> 2, c0 = (tid & 3) * 16;
  const u16* src = V + ((size_t)bh * 1024 + l0 + r) * 64 + c0;
  __align__(16) u16 tmp[16];
  *reinterpret_cast<uint4*>(tmp) = *reinterpret_cast<const uint4*>(src);
  *reinterpret_cast<uint4*>(tmp + 8) = *reinterpret_cast<const uint4*>(src + 8);
  #pragma unroll
  for (int i = 0; i < 16; i++) t[c0 + i][r] = tmp[i];
  __syncthreads();
  __align__(16) u16 o[16];
  #pragma unroll
  for (int i = 0; i < 16; i++) o[i] = t[r][c0 + i];
  u16* dst = Vt + ((size_t)bh * 64 + r) * 1024 + l0 + c0;
  *reinterpret_cast<uint4*>(dst) = *reinterpret_cast<const uint4*>(o);
  *reinterpret_cast<uint4*>(dst + 8) = *reinterpret_cast<const uint4*>(o + 8);
}

// ---------- 5) fused flash attention (swapped-QK^T, KBLK=64, dbuf, swizzled LDS) ----------
// grid (L/64, B*H); block 256 = 4 waves; wave w owns q rows [blk*64+w*16, +16).
// Lane (l15, lg4): q = q0w + l15 throughout (S^T and O^T layouts keep q per-lane).
__global__ __launch_bounds__(256) void k_attn(const u16* __restrict__ Q, const u16* __restrict__ K,
    const u16* __restrict__ Vt, const float* __restrict__ bias, const int* __restrict__ mask,
    const float* __restrict__ gate, u16* __restrict__ O) {
  __shared__ __align__(16) u16 lK[2][4096];      // [buf][64 k][64 d], swizzled
  __shared__ __align__(16) u16 lV[2][4096];      // [buf][64 d][64 k], swizzled
  __shared__ __align__(16) u16 lP[4][16 * 72];   // per-wave [16 q][64 k], stride 72
  const int tid = threadIdx.x;
  const int w = tid >> 6, lane = tid & 63;
  const int l15 = lane & 15, lg4 = lane >> 4;
  const int bh = blockIdx.y;
  const int b = bh >> 4, h = bh & 15;
  const int qg = blockIdx.x * 64 + w * 16 + l15;        // this lane's q row
  const float gateh = gate[h];
  const int* mb = mask + b * 1024;
  const float* biasr = bias + ((size_t)bh << 20) + (size_t)qg * 1024;
  const size_t kvbase = (size_t)bh * 65536;

  // Q fragment (B-operand of S^T): col=q=l15, k-dim=d contiguous
  bf16x8 qf0 = *reinterpret_cast<const bf16x8*>(Q + kvbase + (size_t)qg * 64 + lg4 * 8);
  bf16x8 qf1 = *reinterpret_cast<const bf16x8*>(Q + kvbase + (size_t)qg * 64 + 32 + lg4 * 8);

  f32x4 zero = {0.f, 0.f, 0.f, 0.f};
  float m_i = -INFINITY, l_i = 0.f;
  f32x4 accO[4];
  #pragma unroll
  for (int f = 0; f < 4; f++) accO[f] = zero;

  // staging: thread covers logical row srow(+c*32), 16B slot (lane&7), source col pre-swizzled
  const int srow = w * 8 + (lane >> 3);                  // 0..31
  const int scol = ((lane & 7) ^ (lane >> 3)) * 8;       // swizzle: byte ^= (row&7)<<4
  const int ldst = w * 1024;                             // wave-uniform LDS base (+c*4096)
  const int swz = (l15 & 7) << 4;                        // read-side swizzle

  // prologue: stage tile 0
  #pragma unroll
  for (int c = 0; c < 2; c++) {
    gld16(K + kvbase + (size_t)(c * 32 + srow) * 64 + scol, (char*)lK[0] + c * 4096 + ldst);
    gld16(Vt + kvbase + (size_t)(c * 32 + srow) * 1024 + scol, (char*)lV[0] + c * 4096 + ldst);
  }
  __syncthreads();

  int cur = 0;
  for (int t = 0; t < 16; t++) {
    const int kb = t * 64;
    if (t < 15) {  // prefetch next tile into other buffer (overlaps compute below)
      const int kb2 = kb + 64;
      #pragma unroll
      for (int c = 0; c < 2; c++) {
        gld16(K + kvbase + (size_t)(kb2 + c * 32 + srow) * 64 + scol, (char*)lK[cur ^ 1] + c * 4096 + ldst);
        gld16(Vt + kvbase + (size_t)(c * 32 + srow) * 1024 + kb2 + scol, (char*)lV[cur ^ 1] + c * 4096 + ldst);
      }
    }

    // S^T[k][q] = sum_d K[k][d] Q[q][d] : A=K rows, B=Q rows
    const char* lkb = (const char*)lK[cur];
    f32x4 s[4];
    #pragma unroll
    for (int fn = 0; fn < 4; fn++) {
      const char* rowp = lkb + (fn * 16 + l15) * 128;
      bf16x8 kf0 = *reinterpret_cast<const bf16x8*>(rowp + ((lg4 * 16) ^ swz));
      bf16x8 kf1 = *reinterpret_cast<const bf16x8*>(rowp + ((64 + lg4 * 16) ^ swz));
      s[fn] = MFMA16(kf0, qf0, zero);
      s[fn] = MFMA16(kf1, qf1, s[fn]);
    }

    // logits: scale + gate*bias (float4) + additive key mask (int4) — exact ref formula
    float p[16];
    float pmax = -INFINITY;
    #pragma unroll
    for (int fn = 0; fn < 4; fn++) {
      const int kg = kb + fn * 16 + lg4 * 4;
      float4 b4 = *reinterpret_cast<const float4*>(biasr + kg);
      int4 m4 = *reinterpret_cast<const int4*>(mb + kg);
      #pragma unroll
      for (int j = 0; j < 4; j++) {
        const float bj = (j == 0) ? b4.x : (j == 1) ? b4.y : (j == 2) ? b4.z : b4.w;
        const int mj = (j == 0) ? m4.x : (j == 1) ? m4.y : (j == 2) ? m4.z : m4.w;
        float lgt = s[fn][j] * 0.125f + gateh * bj + (mj ? 0.f : -10000.f);
        p[fn * 4 + j] = lgt;
        pmax = fmaxf(pmax, lgt);
      }
    }
    pmax = fmaxf(pmax, __shfl_xor(pmax, 16));
    pmax = fmaxf(pmax, __shfl_xor(pmax, 32));
    const float mnew = fmaxf(m_i, pmax);
    const float corr = __expf(m_i - mnew);   // m_i=-inf on first tile -> corr=0
    float rs = 0.f;
    #pragma unroll
    for (int i = 0; i < 16; i++) { p[i] = __expf(p[i] - mnew); rs += p[i]; }
    rs += __shfl_xor(rs, 16);
    rs += __shfl_xor(rs, 32);
    l_i = l_i * corr + rs;
    m_i = mnew;
    #pragma unroll
    for (int f = 0; f < 4; f++)
      #pragma unroll
      for (int j = 0; j < 4; j++) accO[f][j] *= corr;

    // pack P^T regs -> lP[q][k] (row-major, stride 72 u16; per-wave private)
    u16* lpw = lP[w];
    #pragma unroll
    for (int fn = 0; fn < 4; fn++) {
      ushort4 pk;
      pk.x = f2bf(p[fn * 4 + 0]); pk.y = f2bf(p[fn * 4 + 1]);
      pk.z = f2bf(p[fn * 4 + 2]); pk.w = f2bf(p[fn * 4 + 3]);
      *reinterpret_cast<ushort4*>(lpw + l15 * 72 + fn * 16 + lg4 * 4) = pk;
    }

    // O^T[d][q] += sum_k Vt[d][k] P[q][k] : A=Vt rows, B=P rows
    bf16x8 pf0 = *reinterpret_cast<const bf16x8*>((const char*)lpw + l15 * 144 + lg4 * 16);
    bf16x8 pf1 = *reinterpret_cast<const bf16x8*>((const char*)lpw + l15 * 144 + 64 + lg4 * 16);
    const char* lvb = (const char*)lV[cur];
    #pragma unroll
    for (int f = 0; f < 4; f++) {
      const char* rowp = lvb + (f * 16 + l15) * 128;
      bf16x8 vf0 = *reinterpret_cast<const bf16x8*>(rowp + ((lg4 * 16) ^ swz));
      bf16x8 vf1 = *reinterpret_cast<const bf16x8*>(rowp + ((64 + lg4 * 16) ^ swz));
      accO[f] = MFMA16(vf0, pf0, accO[f]);
      accO[f] = MFMA16(vf1, pf1, accO[f]);
    }
    __syncthreads();   // drains prefetch vmcnt + protects dbuf swap
    cur ^= 1;
  }

  // epilogue: lane holds O^T[d = f*16+lg4*4+j][q=qg]; /l, * query-mask
  const float sc = (mb[qg] ? 1.f : 0.f) / l_i;   // l_i >= 1 always
  u16* orow = O + (((size_t)(b * 1024 + qg)) * 16 + h) * 64;
  #pragma unroll
  for (int f = 0; f < 4; f++) {
    ushort4 o4;
    o4.x = f2bf(accO[f][0] * sc); o4.y = f2bf(accO[f][1] * sc);
    o4.z = f2bf(accO[f][2] * sc); o4.w = f2bf(accO[f][3] * sc);
    *reinterpret_cast<ushort4*>(orow + f * 16 + lg4 * 4) = o4;
  }
}

// ---------- 6) out = x + O @ Wo^T + bo ----------
__global__ __launch_bounds__(256) void k_gemm_out(const u16* __restrict__ A, const u16* __restrict__ Bt,
    const float* __restrict__ bo, const float* __restrict__ x, float* __restrict__ out) {
  __shared__ __align__(16) u16 lA[128 * 32];
  __shared__ __align__(16) u16 lB[128 * 32];
  const int tid = threadIdx.x;
  const int w = tid >> 6, lane = tid & 63;
  const int wr = w >> 1, wc = w & 1;
  const int lane15 = lane & 15, lgrp = lane >> 4;
  const int m0 = blockIdx.y * 128, n0 = blockIdx.x * 128;

  f32x4 zero = {0.f, 0.f, 0.f, 0.f};
  f32x4 acc[4][4];
  #pragma unroll
  for (int i = 0; i < 4; i++)
    #pragma unroll
    for (int j = 0; j < 4; j++) acc[i][j] = zero;

  const int srow = w * 16 + (lane >> 2);
  const int scol = (lane & 3) * 8;
  for (int kt = 0; kt < 32; kt++) {
    const int k0 = kt * 32;
    #pragma unroll
    for (int c = 0; c < 2; c++) {
      gld16(A + (size_t)(m0 + c * 64 + srow) * 1024 + k0 + scol, (char*)lA + c * 4096 + w * 1024);
      gld16(Bt + (size_t)(n0 + c * 64 + srow) * 1024 + k0 + scol, (char*)lB + c * 4096 + w * 1024);
    }
    __syncthreads();
    bf16x8 aF[4], bF[4];
    #pragma unroll
    for (int f = 0; f < 4; f++) {
      aF[f] = *reinterpret_cast<const bf16x8*>(&lA[(wr * 64 + f * 16 + lane15) * 32 + lgrp * 8]);
      bF[f] = *reinterpret_cast<const bf16x8*>(&lB[(wc * 64 + f * 16 + lane15) * 32 + lgrp * 8]);
    }
    #pragma unroll
    for (int fm = 0; fm < 4; fm++)
      #pragma unroll
      for (int fn = 0; fn < 4; fn++)
        acc[fm][fn] = MFMA16(aF[fm], bF[fn], acc[fm][fn]);
    __syncthreads();
  }

  #pragma unroll
  for (int fm = 0; fm < 4; fm++)
    #pragma unroll
    for (int fn = 0; fn < 4; fn++) {
      const int n = n0 + wc * 64 + fn * 16 + lane15;
      const float bn = bo[n];
      #pragma unroll
      for (int j = 0; j < 4; j++) {
        const int m = m0 + wr * 64 + fm * 16 + lgrp * 4 + j;
        out[(size_t)m * 1024 + n] = acc[fm][fn][j] + bn + x[(size_t)m * 1024 + n];
      }
    }
}

extern "C" void kernel_launch(void* const* d_in, const int* in_sizes, int n_in,
                              void* d_out, int out_size, void* d_ws, size_t ws_size,
                              hipStream_t stream) {
  const float* x     = (const float*)d_in[0];
  const float* bias  = (const float*)d_in[1];
  const int*   mask  = (const int*)d_in[2];
  const float* Wq    = (const float*)d_in[3];
  const float* bq    = (const float*)d_in[4];
  const float* Wk    = (const float*)d_in[5];
  const float* bk    = (const float*)d_in[6];
  const float* Wv    = (const float*)d_in[7];
  const float* bv    = (const float*)d_in[8];
  const float* Wo    = (const float*)d_in[9];
  const float* bo    = (const float*)d_in[10];
  const float* gamma = (const float*)d_in[11];
  const float* beta  = (const float*)d_in[12];
  const float* gate  = (const float*)d_in[13];
  float* out = (float*)d_out;

  u16* wsu  = (u16*)d_ws;
  u16* wqb  = wsu;                  // 1M u16 each
  u16* wkb  = wqb  + (1u << 20);
  u16* wvb  = wkb  + (1u << 20);
  u16* wob  = wvb  + (1u << 20);
  u16* xnb  = wob  + (1u << 20);    // [4096][1024]
  u16* qb   = xnb  + (4u << 20);    // [B,H,L,D]
  u16* kbuf = qb   + (4u << 20);    // [B,H,L,D]
  u16* vb   = kbuf + (4u << 20);    // [B,H,L,D]
  u16* vtb  = vb   + (4u << 20);    // [B,H,D,L]
  u16* ob   = vtb  + (4u << 20);    // [B,L,H*D]
  // total 28M u16 = 56 MB of d_ws

  k_castw<<<4096, 256, 0, stream>>>(Wq, Wk, Wv, Wo, wqb);
  k_ln<<<4096, 256, 0, stream>>>(x, gamma, beta, xnb);
  k_gemm_qkv<<<dim3(8, 32, 3), 256, 0, stream>>>(xnb, wqb, wkb, wvb, bq, bk, bv, qb, kbuf, vb);
  k_transpose_v<<<dim3(16, 64), 256, 0, stream>>>(vb, vtb);
  k_attn<<<dim3(16, 64), 256, 0, stream>>>(qb, kbuf, vtb, bias, mask, gate, ob);
  k_gemm_out<<<dim3(8, 32), 256, 0, stream>>>(ob, wob, bo, x, out);
}

// Round 7
// 511.463 us; speedup vs baseline: 1.1308x; 1.0597x over previous
//
#include <hip/hip_runtime.h>
#include <math.h>

typedef unsigned short u16;
typedef __attribute__((ext_vector_type(8))) short bf16x8;
typedef __attribute__((ext_vector_type(4))) float f32x4;

#define MFMA16(a, b, c) __builtin_amdgcn_mfma_f32_16x16x32_bf16(a, b, c, 0, 0, 0)

__device__ __forceinline__ void gld16(const void* g, void* l) {
  __builtin_amdgcn_global_load_lds((const __attribute__((address_space(1))) void*)g,
                                   (__attribute__((address_space(3))) void*)l, 16, 0, 0);
}

__device__ __forceinline__ u16 f2bf(float f) {  // RNE f32->bf16 (finite inputs)
  unsigned u = __float_as_uint(f);
  u += 0x7fffu + ((u >> 16) & 1u);
  return (u16)(u >> 16);
}

// ---------- 1) cast 4 weight matrices [1024x1024] f32 -> bf16 ----------
__global__ __launch_bounds__(256) void k_castw(const float* __restrict__ wq, const float* __restrict__ wk,
                                               const float* __restrict__ wv, const float* __restrict__ wo,
                                               u16* __restrict__ dst) {
  int t = blockIdx.x * 256 + threadIdx.x;   // 0 .. 2^20-1  (float4 units)
  int which = t >> 18;                      // 2^18 float4 per weight
  int off = (t & 0x3ffff) << 2;
  const float* src = (which == 0) ? wq : (which == 1) ? wk : (which == 2) ? wv : wo;
  float4 v = *reinterpret_cast<const float4*>(src + off);
  ushort4 o;
  o.x = f2bf(v.x); o.y = f2bf(v.y); o.z = f2bf(v.z); o.w = f2bf(v.w);
  *reinterpret_cast<ushort4*>(dst + ((size_t)which << 20) + off) = o;
}

// ---------- 2) LayerNorm -> bf16, one block per row of 1024 ----------
__global__ __launch_bounds__(256) void k_ln(const float* __restrict__ x, const float* __restrict__ gamma,
                                            const float* __restrict__ beta, u16* __restrict__ xn) {
  const int row = blockIdx.x, tid = threadIdx.x;
  const int lane = tid & 63, w = tid >> 6;
  const float* xr = x + (size_t)row * 1024;
  float4 v = *reinterpret_cast<const float4*>(xr + tid * 4);
  float s = v.x + v.y + v.z + v.w;
  float s2 = v.x * v.x + v.y * v.y + v.z * v.z + v.w * v.w;
  #pragma unroll
  for (int m = 1; m < 64; m <<= 1) { s += __shfl_xor(s, m); s2 += __shfl_xor(s2, m); }
  __shared__ float ps[4], pq[4];
  if (lane == 0) { ps[w] = s; pq[w] = s2; }
  __syncthreads();
  float S = ps[0] + ps[1] + ps[2] + ps[3];
  float S2 = pq[0] + pq[1] + pq[2] + pq[3];
  float mu = S * (1.f / 1024.f);
  float var = S2 * (1.f / 1024.f) - mu * mu;
  float rstd = rsqrtf(var + 1e-5f);
  float4 g = *reinterpret_cast<const float4*>(gamma + tid * 4);
  float4 bt = *reinterpret_cast<const float4*>(beta + tid * 4);
  ushort4 o;
  o.x = f2bf((v.x - mu) * rstd * g.x + bt.x);
  o.y = f2bf((v.y - mu) * rstd * g.y + bt.y);
  o.z = f2bf((v.z - mu) * rstd * g.z + bt.z);
  o.w = f2bf((v.w - mu) * rstd * g.w + bt.w);
  *reinterpret_cast<ushort4*>(xn + (size_t)row * 1024 + tid * 4) = o;
}

// ---------- 3) QKV projection: C[m][n] = sum_k xn[m][k] * W[n][k]  (gemm_bt 128x128) ----------
// Q output is pre-scaled by 1/sqrt(D)=0.125 (exact power of two -> bit-identical bf16).
__global__ __launch_bounds__(256) void k_gemm_qkv(const u16* __restrict__ xn,
    const u16* __restrict__ wqb, const u16* __restrict__ wkb, const u16* __restrict__ wvb,
    const float* __restrict__ bq, const float* __restrict__ bk, const float* __restrict__ bv,
    u16* __restrict__ qo, u16* __restrict__ ko, u16* __restrict__ vo) {
  __shared__ __align__(16) u16 lA[128 * 32];
  __shared__ __align__(16) u16 lB[128 * 32];
  const int tid = threadIdx.x;
  const int w = tid >> 6, lane = tid & 63;
  const int wr = w >> 1, wc = w & 1;
  const int lane15 = lane & 15, lgrp = lane >> 4;
  const int m0 = blockIdx.y * 128, n0 = blockIdx.x * 128;
  const int z = blockIdx.z;
  const u16* Bt = (z == 0) ? wqb : (z == 1) ? wkb : wvb;

  f32x4 zero = {0.f, 0.f, 0.f, 0.f};
  f32x4 acc[4][4];
  #pragma unroll
  for (int i = 0; i < 4; i++)
    #pragma unroll
    for (int j = 0; j < 4; j++) acc[i][j] = zero;

  const int srow = w * 16 + (lane >> 2);
  const int scol = (lane & 3) * 8;
  for (int kt = 0; kt < 32; kt++) {
    const int k0 = kt * 32;
    #pragma unroll
    for (int c = 0; c < 2; c++) {
      gld16(xn + (size_t)(m0 + c * 64 + srow) * 1024 + k0 + scol, (char*)lA + c * 4096 + w * 1024);
      gld16(Bt + (size_t)(n0 + c * 64 + srow) * 1024 + k0 + scol, (char*)lB + c * 4096 + w * 1024);
    }
    __syncthreads();
    bf16x8 aF[4], bF[4];
    #pragma unroll
    for (int f = 0; f < 4; f++) {
      aF[f] = *reinterpret_cast<const bf16x8*>(&lA[(wr * 64 + f * 16 + lane15) * 32 + lgrp * 8]);
      bF[f] = *reinterpret_cast<const bf16x8*>(&lB[(wc * 64 + f * 16 + lane15) * 32 + lgrp * 8]);
    }
    #pragma unroll
    for (int fm = 0; fm < 4; fm++)
      #pragma unroll
      for (int fn = 0; fn < 4; fn++)
        acc[fm][fn] = MFMA16(aF[fm], bF[fn], acc[fm][fn]);
    __syncthreads();
  }

  const float* bvec = (z == 0) ? bq : (z == 1) ? bk : bv;
  u16* dst = (z == 0) ? qo : (z == 1) ? ko : vo;
  const float oscale = (z == 0) ? 0.125f : 1.0f;
  #pragma unroll
  for (int fm = 0; fm < 4; fm++)
    #pragma unroll
    for (int fn = 0; fn < 4; fn++) {
      const int n = n0 + wc * 64 + fn * 16 + lane15;
      const int h = n >> 6, d = n & 63;
      const float bn = bvec[n];
      #pragma unroll
      for (int j = 0; j < 4; j++) {
        const int m = m0 + wr * 64 + fm * 16 + lgrp * 4 + j;
        const int b = m >> 10, lq = m & 1023;
        dst[(((size_t)(b * 16 + h)) * 1024 + lq) * 64 + d] = f2bf((acc[fm][fn][j] + bn) * oscale);
      }
    }
}

// ---------- 4) V [B,H,L,D] -> Vt [B,H,D,L] ----------
__global__ __launch_bounds__(256) void k_transpose_v(const u16* __restrict__ V, u16* __restrict__ Vt) {
  __shared__ u16 t[64][64];
  const int bh = blockIdx.y, l0 = blockIdx.x * 64;
  const int tid = threadIdx.x;
  const int r = tid >> 2, c0 = (tid & 3) * 16;
  const u16* src = V + ((size_t)bh * 1024 + l0 + r) * 64 + c0;
  __align__(16) u16 tmp[16];
  *reinterpret_cast<uint4*>(tmp) = *reinterpret_cast<const uint4*>(src);
  *reinterpret_cast<uint4*>(tmp + 8) = *reinterpret_cast<const uint4*>(src + 8);
  #pragma unroll
  for (int i = 0; i < 16; i++) t[c0 + i][r] = tmp[i];
  __syncthreads();
  __align__(16) u16 o[16];
  #pragma unroll
  for (int i = 0; i < 16; i++) o[i] = t[r][c0 + i];
  u16* dst = Vt + ((size_t)bh * 64 + r) * 1024 + l0 + c0;
  *reinterpret_cast<uint4*>(dst) = *reinterpret_cast<const uint4*>(o);
  *reinterpret_cast<uint4*>(dst + 8) = *reinterpret_cast<const uint4*>(o + 8);
}

// ---------- 5) fused flash attention v3 ----------
// grid (L/64, B*H); block 256 = 4 waves; wave w owns q rows [blk*64+w*16, +16).
// Swapped-operand layouts keep q per-lane (q = q0w + l15).
// v3: bias+mask register-prefetched one tile ahead (hides HBM latency);
//     LDS = 40960 B exactly -> 4 blocks/CU; lP swizzled (no pad).
__global__ __launch_bounds__(256, 4) void k_attn(const u16* __restrict__ Q, const u16* __restrict__ K,
    const u16* __restrict__ Vt, const float* __restrict__ bias, const int* __restrict__ mask,
    const float* __restrict__ gate, u16* __restrict__ O) {
  __shared__ __align__(16) u16 lK[2][4096];      // [buf][64 k][64 d], swizzled
  __shared__ __align__(16) u16 lV[2][4096];      // [buf][64 d][64 k], swizzled
  __shared__ __align__(16) u16 lP[4][1024];      // per-wave [16 q][64 k], swizzled
  const int tid = threadIdx.x;
  const int w = tid >> 6, lane = tid & 63;
  const int l15 = lane & 15, lg4 = lane >> 4;
  const int bh = blockIdx.y;
  const int b = bh >> 4, h = bh & 15;
  const int qg = blockIdx.x * 64 + w * 16 + l15;        // this lane's q row
  const float gateh = gate[h];
  const int* mb = mask + b * 1024;
  const float* biasr = bias + ((size_t)bh << 20) + (size_t)qg * 1024;
  const size_t kvbase = (size_t)bh * 65536;

  // Q fragment (B-operand of S^T): col=q=l15, k-dim=d contiguous. Pre-scaled by 0.125.
  bf16x8 qf0 = *reinterpret_cast<const bf16x8*>(Q + kvbase + (size_t)qg * 64 + lg4 * 8);
  bf16x8 qf1 = *reinterpret_cast<const bf16x8*>(Q + kvbase + (size_t)qg * 64 + 32 + lg4 * 8);

  f32x4 zero = {0.f, 0.f, 0.f, 0.f};
  float m_i = -INFINITY, l_i = 0.f;
  f32x4 accO[4];
  #pragma unroll
  for (int f = 0; f < 4; f++) accO[f] = zero;

  // K/V staging: thread covers row srow(+c*32), 16B slot (lane&7), source col pre-swizzled
  const int srow = w * 8 + (lane >> 3);                  // 0..31
  const int scol = ((lane & 7) ^ (lane >> 3)) * 8;       // inverse-swizzle on global source
  const int ldst = w * 1024;                             // wave-uniform LDS base (+c*4096)
  const int swz = (l15 & 7) << 4;                        // read-side swizzle (K/V and P)

  // prologue: stage K/V tile 0; load+combine bias/mask tile 0 into regs
  #pragma unroll
  for (int c = 0; c < 2; c++) {
    gld16(K + kvbase + (size_t)(c * 32 + srow) * 64 + scol, (char*)lK[0] + c * 4096 + ldst);
    gld16(Vt + kvbase + (size_t)(c * 32 + srow) * 1024 + scol, (char*)lV[0] + c * 4096 + ldst);
  }
  f32x4 bcur[4];
  #pragma unroll
  for (int fn = 0; fn < 4; fn++) {
    const int kg = fn * 16 + lg4 * 4;
    float4 b4 = *reinterpret_cast<const float4*>(biasr + kg);
    int4 m4 = *reinterpret_cast<const int4*>(mb + kg);
    bcur[fn][0] = gateh * b4.x + (m4.x ? 0.f : -10000.f);
    bcur[fn][1] = gateh * b4.y + (m4.y ? 0.f : -10000.f);
    bcur[fn][2] = gateh * b4.z + (m4.z ? 0.f : -10000.f);
    bcur[fn][3] = gateh * b4.w + (m4.w ? 0.f : -10000.f);
  }
  __syncthreads();

  int cur = 0;
  for (int t = 0; t < 16; t++) {
    // prefetch next tile: K/V -> LDS (other buffer), bias+mask -> regs
    f32x4 bnext[4];
    if (t < 15) {
      const int kb2 = (t + 1) * 64;
      #pragma unroll
      for (int c = 0; c < 2; c++) {
        gld16(K + kvbase + (size_t)(kb2 + c * 32 + srow) * 64 + scol, (char*)lK[cur ^ 1] + c * 4096 + ldst);
        gld16(Vt + kvbase + (size_t)(c * 32 + srow) * 1024 + kb2 + scol, (char*)lV[cur ^ 1] + c * 4096 + ldst);
      }
      #pragma unroll
      for (int fn = 0; fn < 4; fn++) {
        const int kg = kb2 + fn * 16 + lg4 * 4;
        float4 b4 = *reinterpret_cast<const float4*>(biasr + kg);
        int4 m4 = *reinterpret_cast<const int4*>(mb + kg);
        bnext[fn][0] = gateh * b4.x + (m4.x ? 0.f : -10000.f);
        bnext[fn][1] = gateh * b4.y + (m4.y ? 0.f : -10000.f);
        bnext[fn][2] = gateh * b4.z + (m4.z ? 0.f : -10000.f);
        bnext[fn][3] = gateh * b4.w + (m4.w ? 0.f : -10000.f);
      }
    }

    // S^T[k][q] = sum_d K[k][d] Q[q][d] : A=K rows, B=Q rows (Q pre-scaled)
    const char* lkb = (const char*)lK[cur];
    f32x4 s[4];
    #pragma unroll
    for (int fn = 0; fn < 4; fn++) {
      const char* rowp = lkb + (fn * 16 + l15) * 128;
      bf16x8 kf0 = *reinterpret_cast<const bf16x8*>(rowp + ((lg4 * 16) ^ swz));
      bf16x8 kf1 = *reinterpret_cast<const bf16x8*>(rowp + ((64 + lg4 * 16) ^ swz));
      s[fn] = MFMA16(kf0, qf0, zero);
      s[fn] = MFMA16(kf1, qf1, s[fn]);
    }

    // logits = S + (gate*bias + maskterm)  [prefetched, combined]
    float p[16];
    float pmax = -INFINITY;
    #pragma unroll
    for (int fn = 0; fn < 4; fn++)
      #pragma unroll
      for (int j = 0; j < 4; j++) {
        float lgt = s[fn][j] + bcur[fn][j];
        p[fn * 4 + j] = lgt;
        pmax = fmaxf(pmax, lgt);
      }
    pmax = fmaxf(pmax, __shfl_xor(pmax, 16));
    pmax = fmaxf(pmax, __shfl_xor(pmax, 32));
    const float mnew = fmaxf(m_i, pmax);
    const float corr = __expf(m_i - mnew);   // m_i=-inf on first tile -> corr=0
    float rs = 0.f;
    #pragma unroll
    for (int i = 0; i < 16; i++) { p[i] = __expf(p[i] - mnew); rs += p[i]; }
    rs += __shfl_xor(rs, 16);
    rs += __shfl_xor(rs, 32);
    l_i = l_i * corr + rs;
    m_i = mnew;
    #pragma unroll
    for (int f = 0; f < 4; f++)
      #pragma unroll
      for (int j = 0; j < 4; j++) accO[f][j] *= corr;

    // pack P^T regs -> lP[q][k] (swizzled, per-wave private)
    char* lpw = (char*)lP[w];
    #pragma unroll
    for (int fn = 0; fn < 4; fn++) {
      ushort4 pk;
      pk.x = f2bf(p[fn * 4 + 0]); pk.y = f2bf(p[fn * 4 + 1]);
      pk.z = f2bf(p[fn * 4 + 2]); pk.w = f2bf(p[fn * 4 + 3]);
      *reinterpret_cast<ushort4*>(lpw + ((l15 * 128 + fn * 32 + lg4 * 8) ^ swz)) = pk;
    }

    // O^T[d][q] += sum_k Vt[d][k] P[q][k] : A=Vt rows, B=P rows
    bf16x8 pf0 = *reinterpret_cast<const bf16x8*>(lpw + ((l15 * 128 + lg4 * 16) ^ swz));
    bf16x8 pf1 = *reinterpret_cast<const bf16x8*>(lpw + ((l15 * 128 + 64 + lg4 * 16) ^ swz));
    const char* lvb = (const char*)lV[cur];
    #pragma unroll
    for (int f = 0; f < 4; f++) {
      const char* rowp = lvb + (f * 16 + l15) * 128;
      bf16x8 vf0 = *reinterpret_cast<const bf16x8*>(rowp + ((lg4 * 16) ^ swz));
      bf16x8 vf1 = *reinterpret_cast<const bf16x8*>(rowp + ((64 + lg4 * 16) ^ swz));
      accO[f] = MFMA16(vf0, pf0, accO[f]);
      accO[f] = MFMA16(vf1, pf1, accO[f]);
    }
    __syncthreads();   // drains prefetch vmcnt + protects dbuf swap
    if (t < 15) {
      #pragma unroll
      for (int fn = 0; fn < 4; fn++) bcur[fn] = bnext[fn];
    }
    cur ^= 1;
  }

  // epilogue: lane holds O^T[d = f*16+lg4*4+j][q=qg]; /l, * query-mask
  const float sc = (mb[qg] ? 1.f : 0.f) / l_i;   // l_i >= 1 always
  u16* orow = O + (((size_t)(b * 1024 + qg)) * 16 + h) * 64;
  #pragma unroll
  for (int f = 0; f < 4; f++) {
    ushort4 o4;
    o4.x = f2bf(accO[f][0] * sc); o4.y = f2bf(accO[f][1] * sc);
    o4.z = f2bf(accO[f][2] * sc); o4.w = f2bf(accO[f][3] * sc);
    *reinterpret_cast<ushort4*>(orow + f * 16 + lg4 * 4) = o4;
  }
}

// ---------- 6) out = x + O @ Wo^T + bo ----------
__global__ __launch_bounds__(256) void k_gemm_out(const u16* __restrict__ A, const u16* __restrict__ Bt,
    const float* __restrict__ bo, const float* __restrict__ x, float* __restrict__ out) {
  __shared__ __align__(16) u16 lA[128 * 32];
  __shared__ __align__(16) u16 lB[128 * 32];
  const int tid = threadIdx.x;
  const int w = tid >> 6, lane = tid & 63;
  const int wr = w >> 1, wc = w & 1;
  const int lane15 = lane & 15, lgrp = lane >> 4;
  const int m0 = blockIdx.y * 128, n0 = blockIdx.x * 128;

  f32x4 zero = {0.f, 0.f, 0.f, 0.f};
  f32x4 acc[4][4];
  #pragma unroll
  for (int i = 0; i < 4; i++)
    #pragma unroll
    for (int j = 0; j < 4; j++) acc[i][j] = zero;

  const int srow = w * 16 + (lane >> 2);
  const int scol = (lane & 3) * 8;
  for (int kt = 0; kt < 32; kt++) {
    const int k0 = kt * 32;
    #pragma unroll
    for (int c = 0; c < 2; c++) {
      gld16(A + (size_t)(m0 + c * 64 + srow) * 1024 + k0 + scol, (char*)lA + c * 4096 + w * 1024);
      gld16(Bt + (size_t)(n0 + c * 64 + srow) * 1024 + k0 + scol, (char*)lB + c * 4096 + w * 1024);
    }
    __syncthreads();
    bf16x8 aF[4], bF[4];
    #pragma unroll
    for (int f = 0; f < 4; f++) {
      aF[f] = *reinterpret_cast<const bf16x8*>(&lA[(wr * 64 + f * 16 + lane15) * 32 + lgrp * 8]);
      bF[f] = *reinterpret_cast<const bf16x8*>(&lB[(wc * 64 + f * 16 + lane15) * 32 + lgrp * 8]);
    }
    #pragma unroll
    for (int fm = 0; fm < 4; fm++)
      #pragma unroll
      for (int fn = 0; fn < 4; fn++)
        acc[fm][fn] = MFMA16(aF[fm], bF[fn], acc[fm][fn]);
    __syncthreads();
  }

  #pragma unroll
  for (int fm = 0; fm < 4; fm++)
    #pragma unroll
    for (int fn = 0; fn < 4; fn++) {
      const int n = n0 + wc * 64 + fn * 16 + lane15;
      const float bn = bo[n];
      #pragma unroll
      for (int j = 0; j < 4; j++) {
        const int m = m0 + wr * 64 + fm * 16 + lgrp * 4 + j;
        out[(size_t)m * 1024 + n] = acc[fm][fn][j] + bn + x[(size_t)m * 1024 + n];
      }
    }
}

extern "C" void kernel_launch(void* const* d_in, const int* in_sizes, int n_in,
                              void* d_out, int out_size, void* d_ws, size_t ws_size,
                              hipStream_t stream) {
  const float* x     = (const float*)d_in[0];
  const float* bias  = (const float*)d_in[1];
  const int*   mask  = (const int*)d_in[2];
  const float* Wq    = (const float*)d_in[3];
  const float* bq    = (const float*)d_in[4];
  const float* Wk    = (const float*)d_in[5];
  const float* bk    = (const float*)d_in[6];
  const float* Wv    = (const float*)d_in[7];
  const float* bv    = (const float*)d_in[8];
  const float* Wo    = (const float*)d_in[9];
  const float* bo    = (const float*)d_in[10];
  const float* gamma = (const float*)d_in[11];
  const float* beta  = (const float*)d_in[12];
  const float* gate  = (const float*)d_in[13];
  float* out = (float*)d_out;

  u16* wsu  = (u16*)d_ws;
  u16* wqb  = wsu;                  // 1M u16 each
  u16* wkb  = wqb  + (1u << 20);
  u16* wvb  = wkb  + (1u << 20);
  u16* wob  = wvb  + (1u << 20);
  u16* xnb  = wob  + (1u << 20);    // [4096][1024]
  u16* qb   = xnb  + (4u << 20);    // [B,H,L,D]
  u16* kbuf = qb   + (4u << 20);    // [B,H,L,D]
  u16* vb   = kbuf + (4u << 20);    // [B,H,L,D]
  u16* vtb  = vb   + (4u << 20);    // [B,H,D,L]
  u16* ob   = vtb  + (4u << 20);    // [B,L,H*D]
  // total 28M u16 = 56 MB of d_ws

  k_castw<<<4096, 256, 0, stream>>>(Wq, Wk, Wv, Wo, wqb);
  k_ln<<<4096, 256, 0, stream>>>(x, gamma, beta, xnb);
  k_gemm_qkv<<<dim3(8, 32, 3), 256, 0, stream>>>(xnb, wqb, wkb, wvb, bq, bk, bv, qb, kbuf, vb);
  k_transpose_v<<<dim3(16, 64), 256, 0, stream>>>(vb, vtb);
  k_attn<<<dim3(16, 64), 256, 0, stream>>>(qb, kbuf, vtb, bias, mask, gate, ob);
  k_gemm_out<<<dim3(8, 32), 256, 0, stream>>>(ob, wob, bo, x, out);
}